// Round 1
// baseline (380.750 us; speedup 1.0000x reference)
//
#include <hip/hip_runtime.h>
#include <math.h>

#define NB 4
#define SEQ 4096
#define NH 32
#define HD 128
#define DIM 4096
#define INTER 11008
#define HC 32
#define HEAVY 256
#define EPS 1e-5f

__device__ __forceinline__ float dot4(float4 a, float4 b) {
  return a.x*b.x + a.y*b.y + a.z*b.z + a.w*b.w;
}

__device__ __forceinline__ float wave_sum(float v) {
  #pragma unroll
  for (int off = 32; off; off >>= 1) v += __shfl_down(v, off, 64);
  return v;
}

// ---------------- RMSNorm: one block per batch row ----------------
__global__ __launch_bounds__(256) void rmsnorm_k(const float* __restrict__ x,
                                                 const float* __restrict__ w,
                                                 float* __restrict__ out) {
  int b = blockIdx.x;
  int tid = threadIdx.x;
  const float4* x4 = (const float4*)(x + (size_t)b * DIM);
  const float4* w4 = (const float4*)w;
  float4* o4 = (float4*)(out + (size_t)b * DIM);
  float ss = 0.f;
  for (int i = tid; i < DIM/4; i += 256) {
    float4 v = x4[i];
    ss += v.x*v.x + v.y*v.y + v.z*v.z + v.w*v.w;
  }
  __shared__ float red[4];
  __shared__ float s_rs;
  ss = wave_sum(ss);
  if ((tid & 63) == 0) red[tid >> 6] = ss;
  __syncthreads();
  if (tid == 0) {
    float t = red[0] + red[1] + red[2] + red[3];
    s_rs = rsqrtf(t / (float)DIM + EPS);
  }
  __syncthreads();
  float rs = s_rs;
  for (int i = tid; i < DIM/4; i += 256) {
    float4 v = x4[i], wv = w4[i];
    float4 r;
    r.x = v.x*rs*wv.x; r.y = v.y*rs*wv.y; r.z = v.z*rs*wv.z; r.w = v.w*rs*wv.w;
    o4[i] = r;
  }
}

// ---------------- QKV GEMV: one block per output row, 4 batches ----------------
__global__ __launch_bounds__(256) void gemv_qkv_k(const float* __restrict__ w,
                                                  const float* __restrict__ xn,
                                                  float* __restrict__ qkv) {
  int r = blockIdx.x;
  const float4* wr = (const float4*)(w + (size_t)r * DIM);
  const float4* x0 = (const float4*)(xn);
  const float4* x1 = (const float4*)(xn + DIM);
  const float4* x2 = (const float4*)(xn + 2*DIM);
  const float4* x3 = (const float4*)(xn + 3*DIM);
  float a0=0.f, a1=0.f, a2=0.f, a3=0.f;
  for (int i = threadIdx.x; i < DIM/4; i += 256) {
    float4 wv = wr[i];
    a0 += dot4(wv, x0[i]);
    a1 += dot4(wv, x1[i]);
    a2 += dot4(wv, x2[i]);
    a3 += dot4(wv, x3[i]);
  }
  a0 = wave_sum(a0); a1 = wave_sum(a1); a2 = wave_sum(a2); a3 = wave_sum(a3);
  __shared__ float red[4][4];
  int lane = threadIdx.x & 63, wv_ = threadIdx.x >> 6;
  if (lane == 0) { red[wv_][0]=a0; red[wv_][1]=a1; red[wv_][2]=a2; red[wv_][3]=a3; }
  __syncthreads();
  if (threadIdx.x < NB) {
    int b = threadIdx.x;
    float s = red[0][b]+red[1][b]+red[2][b]+red[3][b];
    qkv[(size_t)b*3*DIM + r] = s;
  }
}

// ---------------- RoPE (in-place in ws qkv) + label-channel gather ----------------
__global__ __launch_bounds__(64) void rope_lab_k(float* __restrict__ qkv,
                                                 const float* __restrict__ freqs,
                                                 const int* __restrict__ sorted_channel,
                                                 float* __restrict__ qlab,
                                                 float* __restrict__ klab) {
  int bh = blockIdx.x; int b = bh >> 5; int h = bh & 31;
  int t = threadIdx.x; // 64 threads, one rotation pair each
  __shared__ float qs[HD], ks[HD];
  float* q = qkv + (size_t)b*3*DIM + h*HD;
  float* k = q + DIM;
  float c = freqs[2*t], sn = freqs[2*t+1];
  float q0 = q[2*t], q1 = q[2*t+1];
  float k0 = k[2*t], k1 = k[2*t+1];
  float qr = q0*c - q1*sn, qi = q1*c + q0*sn;
  float kr = k0*c - k1*sn, ki = k1*c + k0*sn;
  q[2*t] = qr; q[2*t+1] = qi;
  k[2*t] = kr; k[2*t+1] = ki;
  qs[2*t] = qr; qs[2*t+1] = qi;
  ks[2*t] = kr; ks[2*t+1] = ki;
  __syncthreads();
  if (t < HC) {
    int ch = sorted_channel[h*HC + t];
    qlab[(size_t)(b*NH + h)*HC + t] = qs[ch];
    klab[(size_t)(b*NH + h)*HC + t] = ks[ch];
  }
}

// ---------------- label scores + radix-select top-256 ----------------
__global__ __launch_bounds__(256) void topk_k(const float* __restrict__ klab_cache,
                                              const float* __restrict__ qlab,
                                              const float* __restrict__ klab,
                                              const int* __restrict__ pos_p,
                                              int* __restrict__ idx_out) {
  int bh = blockIdx.x; int b = bh >> 5; int h = bh & 31;
  int pos = *pos_p;
  int n = pos + 1;                       // candidates 0..pos (others masked -1e9)
  __shared__ uint32_t su[SEQ];
  __shared__ uint32_t hist[256];
  __shared__ uint32_t sh_prefix, sh_kremain, sh_cnt;
  __shared__ float qv[HC];
  int tid = threadIdx.x;
  if (tid < HC) qv[tid] = qlab[(size_t)(b*NH + h)*HC + tid];
  if (tid == 0) { sh_prefix = 0; sh_kremain = HEAVY; sh_cnt = 0; }
  __syncthreads();
  for (int s = tid; s < n; s += 256) {
    const float* kl = (s == pos) ? (klab + (size_t)(b*NH + h)*HC)
                                 : (klab_cache + (((size_t)b*SEQ + s)*NH + h)*HC);
    const float4* kl4 = (const float4*)kl;
    float acc = 0.f;
    #pragma unroll
    for (int c4 = 0; c4 < HC/4; c4++) {
      float4 kvv = kl4[c4];
      acc += qv[c4*4+0]*kvv.x + qv[c4*4+1]*kvv.y + qv[c4*4+2]*kvv.z + qv[c4*4+3]*kvv.w;
    }
    uint32_t u = __float_as_uint(acc);
    u = (u & 0x80000000u) ? ~u : (u | 0x80000000u);   // monotone map, desc order
    su[s] = u;
  }
  __syncthreads();
  uint32_t prefix = 0;
  #pragma unroll
  for (int pass = 0; pass < 4; pass++) {
    int shift = 24 - 8*pass;
    for (int i = tid; i < 256; i += 256) hist[i] = 0;
    __syncthreads();
    for (int s = tid; s < n; s += 256) {
      uint32_t u = su[s];
      bool match = (pass == 0) || ((u >> (shift + 8)) == prefix);
      if (match) atomicAdd(&hist[(u >> shift) & 255u], 1u);
    }
    __syncthreads();
    if (tid == 0) {
      uint32_t need = sh_kremain, c = 0;
      int d = 255;
      for (; d >= 0; d--) {
        if (c + hist[d] >= need) break;
        c += hist[d];
      }
      if (d < 0) d = 0;                 // safety
      sh_kremain = need - c;
      sh_prefix = (sh_prefix << 8) | (uint32_t)d;
    }
    __syncthreads();
    prefix = sh_prefix;
  }
  uint32_t T = prefix;                   // exact value of the 256th-largest
  int* outp = idx_out + (size_t)(b*NH + h)*HEAVY;
  for (int s = tid; s < n; s += 256) {
    if (su[s] > T) { uint32_t p = atomicAdd(&sh_cnt, 1u); outp[p] = s; }
  }
  __syncthreads();
  for (int s = tid; s < n; s += 256) {
    if (su[s] == T) {
      uint32_t p = atomicAdd(&sh_cnt, 1u);
      if (p < HEAVY) outp[p] = s;
    }
  }
}

// ---------------- gather attention over 256 selected tokens ----------------
__global__ __launch_bounds__(256) void attn_k(const float* __restrict__ k_cache,
                                              const float* __restrict__ v_cache,
                                              const float* __restrict__ qkv,
                                              const int* __restrict__ idx,
                                              const int* __restrict__ pos_p,
                                              float* __restrict__ o) {
  int bh = blockIdx.x; int b = bh >> 5; int h = bh & 31;
  int pos = *pos_p;
  int tid = threadIdx.x;
  __shared__ int lidx[HEAVY];
  __shared__ float sc[HEAVY];
  __shared__ float ov[256];
  __shared__ float red[8];
  __shared__ float s_m, s_sum;
  lidx[tid] = idx[(size_t)(b*NH + h)*HEAVY + tid];
  __syncthreads();
  const float* qp   = qkv + (size_t)b*3*DIM + h*HD;
  const float* knew = qp + DIM;
  const float* vnew = qp + 2*DIM;
  int g = tid >> 5, l = tid & 31;        // 8 groups of 32 lanes
  float4 q4 = ((const float4*)qp)[l];
  for (int j = g; j < HEAVY; j += 8) {
    int s = lidx[j];
    const float* kp = (s == pos) ? knew
                                 : (k_cache + (((size_t)b*SEQ + s)*NH + h)*HD);
    float4 k4 = ((const float4*)kp)[l];
    float p = dot4(q4, k4);
    #pragma unroll
    for (int off = 16; off; off >>= 1) p += __shfl_xor(p, off, 64);
    if (l == 0) sc[j] = p * 0.088388347648318447f;   // 1/sqrt(128)
  }
  __syncthreads();
  // softmax over the 256 scores; each thread owns sc[tid]
  float v = sc[tid];
  float m = v;
  #pragma unroll
  for (int off = 32; off; off >>= 1) m = fmaxf(m, __shfl_xor(m, off, 64));
  if ((tid & 63) == 0) red[tid >> 6] = m;
  __syncthreads();
  if (tid == 0) {
    float mm = red[0];
    for (int i = 1; i < 4; i++) mm = fmaxf(mm, red[i]);
    s_m = mm;
  }
  __syncthreads();
  float p = expf(v - s_m);
  float sum = p;
  #pragma unroll
  for (int off = 32; off; off >>= 1) sum += __shfl_xor(sum, off, 64);
  if ((tid & 63) == 0) red[4 + (tid >> 6)] = sum;
  __syncthreads();
  if (tid == 0) {
    float ss = 0;
    for (int i = 0; i < 4; i++) ss += red[4 + i];
    s_sum = ss;
  }
  __syncthreads();
  sc[tid] = p / s_sum;
  __syncthreads();
  // PV: threads 0..127 handle even j, 128..255 odd j; d = tid & 127
  int d = tid & 127, half = tid >> 7;
  float acc = 0.f;
  for (int j = half; j < HEAVY; j += 2) {
    int s = lidx[j];
    const float* vp = (s == pos) ? vnew
                                 : (v_cache + (((size_t)b*SEQ + s)*NH + h)*HD);
    acc += sc[j] * vp[d];
  }
  ov[tid] = acc;
  __syncthreads();
  if (tid < 128) o[(size_t)(b*NH + h)*HD + tid] = ov[tid] + ov[tid + 128];
}

// ---------------- Wo GEMV + residual ----------------
__global__ __launch_bounds__(256) void gemv_wo_k(const float* __restrict__ w,
                                                 const float* __restrict__ oin,
                                                 const float* __restrict__ x,
                                                 float* __restrict__ hout) {
  int r = blockIdx.x;
  const float4* wr = (const float4*)(w + (size_t)r * DIM);
  float a[NB] = {0,0,0,0};
  for (int i = threadIdx.x; i < DIM/4; i += 256) {
    float4 wv = wr[i];
    #pragma unroll
    for (int b = 0; b < NB; b++)
      a[b] += dot4(wv, ((const float4*)(oin + (size_t)b*DIM))[i]);
  }
  #pragma unroll
  for (int b = 0; b < NB; b++) a[b] = wave_sum(a[b]);
  __shared__ float red[4][4];
  int lane = threadIdx.x & 63, wv_ = threadIdx.x >> 6;
  if (lane == 0) { for (int b = 0; b < NB; b++) red[wv_][b] = a[b]; }
  __syncthreads();
  if (threadIdx.x < NB) {
    int b = threadIdx.x;
    float s = red[0][b]+red[1][b]+red[2][b]+red[3][b];
    hout[(size_t)b*DIM + r] = x[(size_t)b*DIM + r] + s;
  }
}

// ---------------- W1/W3 GEMV + SwiGLU ----------------
__global__ __launch_bounds__(256) void gemv_ffn13_k(const float* __restrict__ w1,
                                                    const float* __restrict__ w3,
                                                    const float* __restrict__ hn,
                                                    float* __restrict__ g) {
  int r = blockIdx.x;
  const float4* w1r = (const float4*)(w1 + (size_t)r * DIM);
  const float4* w3r = (const float4*)(w3 + (size_t)r * DIM);
  float a1[NB] = {0,0,0,0}, a3[NB] = {0,0,0,0};
  for (int i = threadIdx.x; i < DIM/4; i += 256) {
    float4 v1 = w1r[i], v3 = w3r[i];
    #pragma unroll
    for (int b = 0; b < NB; b++) {
      float4 xv = ((const float4*)(hn + (size_t)b*DIM))[i];
      a1[b] += dot4(v1, xv);
      a3[b] += dot4(v3, xv);
    }
  }
  #pragma unroll
  for (int b = 0; b < NB; b++) { a1[b] = wave_sum(a1[b]); a3[b] = wave_sum(a3[b]); }
  __shared__ float red[4][8];
  int lane = threadIdx.x & 63, wv_ = threadIdx.x >> 6;
  if (lane == 0) {
    #pragma unroll
    for (int b = 0; b < NB; b++) { red[wv_][b] = a1[b]; red[wv_][4+b] = a3[b]; }
  }
  __syncthreads();
  if (threadIdx.x < NB) {
    int b = threadIdx.x;
    float d1 = red[0][b]+red[1][b]+red[2][b]+red[3][b];
    float d3 = red[0][4+b]+red[1][4+b]+red[2][4+b]+red[3][4+b];
    float s = d1 / (1.f + expf(-d1));    // silu
    g[(size_t)b*INTER + r] = s * d3;
  }
}

// ---------------- W2 GEMV + residual -> final output ----------------
__global__ __launch_bounds__(256) void gemv_w2_k(const float* __restrict__ w2,
                                                 const float* __restrict__ g,
                                                 const float* __restrict__ h,
                                                 float* __restrict__ out) {
  int r = blockIdx.x;
  const float4* wr = (const float4*)(w2 + (size_t)r * INTER);
  float a[NB] = {0,0,0,0};
  for (int i = threadIdx.x; i < INTER/4; i += 256) {
    float4 wv = wr[i];
    #pragma unroll
    for (int b = 0; b < NB; b++)
      a[b] += dot4(wv, ((const float4*)(g + (size_t)b*INTER))[i]);
  }
  #pragma unroll
  for (int b = 0; b < NB; b++) a[b] = wave_sum(a[b]);
  __shared__ float red[4][4];
  int lane = threadIdx.x & 63, wv_ = threadIdx.x >> 6;
  if (lane == 0) { for (int b = 0; b < NB; b++) red[wv_][b] = a[b]; }
  __syncthreads();
  if (threadIdx.x < NB) {
    int b = threadIdx.x;
    float s = red[0][b]+red[1][b]+red[2][b]+red[3][b];
    out[(size_t)b*DIM + r] = h[(size_t)b*DIM + r] + s;
  }
}

extern "C" void kernel_launch(void* const* d_in, const int* in_sizes, int n_in,
                              void* d_out, int out_size, void* d_ws, size_t ws_size,
                              hipStream_t stream) {
  const float* x              = (const float*)d_in[0];
  const float* wqkv           = (const float*)d_in[1];
  const float* wo             = (const float*)d_in[2];
  const float* w1             = (const float*)d_in[3];
  const float* w2             = (const float*)d_in[4];
  const float* w3             = (const float*)d_in[5];
  const float* attn_norm_w    = (const float*)d_in[6];
  const float* ffn_norm_w     = (const float*)d_in[7];
  const float* k_cache        = (const float*)d_in[8];
  const float* v_cache        = (const float*)d_in[9];
  const float* k_label_cache  = (const float*)d_in[10];
  const float* freqs          = (const float*)d_in[11];
  // d_in[12] = mask1 (semantics: 0 for s<=pos, -1e9 else) — implemented via s range
  const int*   sorted_channel = (const int*)d_in[13];
  const int*   pos_p          = (const int*)d_in[14];
  // d_in[15] = heavy_const (fixed 256, hardcoded as HEAVY)

  float* ws  = (float*)d_ws;
  float* xn   = ws;                       // 4*4096
  float* qkv  = xn  + NB*DIM;             // 4*12288 (q,k roped in place)
  float* qlab = qkv + NB*3*DIM;           // 4*32*32
  float* klab = qlab + NB*NH*HC;          // 4*32*32
  int*   idx  = (int*)(klab + NB*NH*HC);  // 4*32*256
  float* o    = (float*)(idx + NB*NH*HEAVY); // 4*4096
  float* h    = o  + NB*DIM;              // 4*4096
  float* hn   = h  + NB*DIM;              // 4*4096
  float* g    = hn + NB*DIM;              // 4*11008

  rmsnorm_k  <<<NB,      256, 0, stream>>>(x, attn_norm_w, xn);
  gemv_qkv_k <<<3*DIM,   256, 0, stream>>>(wqkv, xn, qkv);
  rope_lab_k <<<NB*NH,    64, 0, stream>>>(qkv, freqs, sorted_channel, qlab, klab);
  topk_k     <<<NB*NH,   256, 0, stream>>>(k_label_cache, qlab, klab, pos_p, idx);
  attn_k     <<<NB*NH,   256, 0, stream>>>(k_cache, v_cache, qkv, idx, pos_p, o);
  gemv_wo_k  <<<DIM,     256, 0, stream>>>(wo, o, x, h);
  rmsnorm_k  <<<NB,      256, 0, stream>>>(h, ffn_norm_w, hn);
  gemv_ffn13_k<<<INTER,  256, 0, stream>>>(w1, w3, hn, g);
  gemv_w2_k  <<<DIM,     256, 0, stream>>>(w2, g, h, (float*)d_out);
}

// Round 2
// 355.101 us; speedup vs baseline: 1.0722x; 1.0722x over previous
//
#include <hip/hip_runtime.h>
#include <math.h>

#define NB 4
#define SEQ 4096
#define NH 32
#define HD 128
#define DIM 4096
#define INTER 11008
#define HC 32
#define HEAVY 256
#define EPS 1e-5f

__device__ __forceinline__ float dot4(float4 a, float4 b) {
  return a.x*b.x + a.y*b.y + a.z*b.z + a.w*b.w;
}

__device__ __forceinline__ float wave_sum(float v) {
  #pragma unroll
  for (int off = 32; off; off >>= 1) v += __shfl_down(v, off, 64);
  return v;
}

// ---------------- RMSNorm: one block per batch row ----------------
__global__ __launch_bounds__(256) void rmsnorm_k(const float* __restrict__ x,
                                                 const float* __restrict__ w,
                                                 float* __restrict__ out) {
  int b = blockIdx.x;
  int tid = threadIdx.x;
  const float4* x4 = (const float4*)(x + (size_t)b * DIM);
  const float4* w4 = (const float4*)w;
  float4* o4 = (float4*)(out + (size_t)b * DIM);
  float ss = 0.f;
  for (int i = tid; i < DIM/4; i += 256) {
    float4 v = x4[i];
    ss += v.x*v.x + v.y*v.y + v.z*v.z + v.w*v.w;
  }
  __shared__ float red[4];
  __shared__ float s_rs;
  ss = wave_sum(ss);
  if ((tid & 63) == 0) red[tid >> 6] = ss;
  __syncthreads();
  if (tid == 0) {
    float t = red[0] + red[1] + red[2] + red[3];
    s_rs = rsqrtf(t / (float)DIM + EPS);
  }
  __syncthreads();
  float rs = s_rs;
  for (int i = tid; i < DIM/4; i += 256) {
    float4 v = x4[i], wv = w4[i];
    float4 r;
    r.x = v.x*rs*wv.x; r.y = v.y*rs*wv.y; r.z = v.z*rs*wv.z; r.w = v.w*rs*wv.w;
    o4[i] = r;
  }
}

// ---------- GEMV, K multiple of 1024: R rows/block, x in registers ----------
// thread t owns columns {j*1024 + 4t .. +3}, j = 0..K/1024-1
template<int K, int R, bool RESID>
__global__ __launch_bounds__(256) void gemv_reg_k(const float* __restrict__ w,
                                                  const float* __restrict__ x,
                                                  const float* __restrict__ resid,
                                                  float* __restrict__ out,
                                                  int ostride) {
  constexpr int J = K / 1024;
  const int t = threadIdx.x;
  const int r0 = blockIdx.x * R;
  float4 xr[NB][J];
  #pragma unroll
  for (int b = 0; b < NB; ++b)
    #pragma unroll
    for (int j = 0; j < J; ++j)
      xr[b][j] = ((const float4*)x)[b*(K/4) + j*256 + t];
  float acc[R][NB];
  #pragma unroll
  for (int r = 0; r < R; ++r)
    #pragma unroll
    for (int b = 0; b < NB; ++b) acc[r][b] = 0.f;
  #pragma unroll
  for (int r = 0; r < R; ++r) {
    const float4* wr = (const float4*)(w + (size_t)(r0 + r) * K);
    #pragma unroll
    for (int j = 0; j < J; ++j) {
      float4 wv = wr[j*256 + t];
      #pragma unroll
      for (int b = 0; b < NB; ++b) acc[r][b] += dot4(wv, xr[b][j]);
    }
  }
  __shared__ float red[4][R*NB];
  const int lane = t & 63, wi = t >> 6;
  #pragma unroll
  for (int r = 0; r < R; ++r)
    #pragma unroll
    for (int b = 0; b < NB; ++b) {
      float v = wave_sum(acc[r][b]);
      if (lane == 0) red[wi][r*NB + b] = v;
    }
  __syncthreads();
  if (t < R*NB) {
    int r = t >> 2, b = t & 3;
    float s = red[0][t] + red[1][t] + red[2][t] + red[3][t];
    if constexpr (RESID) s += resid[(size_t)b*ostride + r0 + r];
    out[(size_t)b*ostride + r0 + r] = s;
  }
}

// ---------- fused W1/W3 GEMV + SwiGLU, register-x, R rows/block ----------
template<int R>
__global__ __launch_bounds__(256) void gemv_ffn13_k(const float* __restrict__ w1,
                                                    const float* __restrict__ w3,
                                                    const float* __restrict__ x,
                                                    float* __restrict__ g) {
  constexpr int J = DIM / 1024;
  const int t = threadIdx.x;
  const int r0 = blockIdx.x * R;
  float4 xr[NB][J];
  #pragma unroll
  for (int b = 0; b < NB; ++b)
    #pragma unroll
    for (int j = 0; j < J; ++j)
      xr[b][j] = ((const float4*)x)[b*(DIM/4) + j*256 + t];
  float a1[R][NB], a3[R][NB];
  #pragma unroll
  for (int r = 0; r < R; ++r)
    #pragma unroll
    for (int b = 0; b < NB; ++b) { a1[r][b] = 0.f; a3[r][b] = 0.f; }
  #pragma unroll
  for (int r = 0; r < R; ++r) {
    const float4* wr1 = (const float4*)(w1 + (size_t)(r0 + r) * DIM);
    const float4* wr3 = (const float4*)(w3 + (size_t)(r0 + r) * DIM);
    #pragma unroll
    for (int j = 0; j < J; ++j) {
      float4 v1 = wr1[j*256 + t];
      float4 v3 = wr3[j*256 + t];
      #pragma unroll
      for (int b = 0; b < NB; ++b) {
        a1[r][b] += dot4(v1, xr[b][j]);
        a3[r][b] += dot4(v3, xr[b][j]);
      }
    }
  }
  __shared__ float red[4][2*R*NB];
  const int lane = t & 63, wi = t >> 6;
  #pragma unroll
  for (int r = 0; r < R; ++r)
    #pragma unroll
    for (int b = 0; b < NB; ++b) {
      float v = wave_sum(a1[r][b]);
      if (lane == 0) red[wi][r*NB + b] = v;
      v = wave_sum(a3[r][b]);
      if (lane == 0) red[wi][R*NB + r*NB + b] = v;
    }
  __syncthreads();
  if (t < R*NB) {
    int r = t >> 2, b = t & 3;
    float d1 = red[0][t] + red[1][t] + red[2][t] + red[3][t];
    int t3 = R*NB + t;
    float d3 = red[0][t3] + red[1][t3] + red[2][t3] + red[3][t3];
    float s = d1 / (1.f + expf(-d1));
    g[(size_t)b*INTER + r0 + r] = s * d3;
  }
}

// ---------- W2 GEMV (K=11008): LDS-tiled x, R rows/block, + residual ----------
template<int R>
__global__ __launch_bounds__(256) void gemv_w2_k(const float* __restrict__ w2,
                                                 const float* __restrict__ g,
                                                 const float* __restrict__ h,
                                                 float* __restrict__ out) {
  const int t = threadIdx.x;
  const int r0 = blockIdx.x * R;
  __shared__ float4 xs[NB][256];   // 16 KB tile: 1024 floats x 4 batches
  float acc[R][NB];
  #pragma unroll
  for (int r = 0; r < R; ++r)
    #pragma unroll
    for (int b = 0; b < NB; ++b) acc[r][b] = 0.f;
  for (int k0 = 0; k0 < INTER; k0 += 1024) {
    const int kn4 = min(256, (INTER - k0) >> 2);   // 256 or 192
    __syncthreads();
    if (t < kn4) {
      #pragma unroll
      for (int b = 0; b < NB; ++b)
        xs[b][t] = ((const float4*)g)[b*(INTER/4) + (k0 >> 2) + t];
    }
    __syncthreads();
    if (t < kn4) {
      #pragma unroll
      for (int r = 0; r < R; ++r) {
        float4 wv = ((const float4*)(w2 + (size_t)(r0 + r) * INTER + k0))[t];
        #pragma unroll
        for (int b = 0; b < NB; ++b) acc[r][b] += dot4(wv, xs[b][t]);
      }
    }
  }
  __shared__ float red[4][R*NB];
  const int lane = t & 63, wi = t >> 6;
  #pragma unroll
  for (int r = 0; r < R; ++r)
    #pragma unroll
    for (int b = 0; b < NB; ++b) {
      float v = wave_sum(acc[r][b]);
      if (lane == 0) red[wi][r*NB + b] = v;
    }
  __syncthreads();
  if (t < R*NB) {
    int r = t >> 2, b = t & 3;
    float s = red[0][t] + red[1][t] + red[2][t] + red[3][t];
    out[(size_t)b*DIM + r0 + r] = h[(size_t)b*DIM + r0 + r] + s;
  }
}

// ---------------- RoPE (in-place in ws qkv) + label-channel gather ----------------
__global__ __launch_bounds__(64) void rope_lab_k(float* __restrict__ qkv,
                                                 const float* __restrict__ freqs,
                                                 const int* __restrict__ sorted_channel,
                                                 float* __restrict__ qlab,
                                                 float* __restrict__ klab) {
  int bh = blockIdx.x; int b = bh >> 5; int h = bh & 31;
  int t = threadIdx.x; // 64 threads, one rotation pair each
  __shared__ float qs[HD], ks[HD];
  float* q = qkv + (size_t)b*3*DIM + h*HD;
  float* k = q + DIM;
  float c = freqs[2*t], sn = freqs[2*t+1];
  float q0 = q[2*t], q1 = q[2*t+1];
  float k0 = k[2*t], k1 = k[2*t+1];
  float qr = q0*c - q1*sn, qi = q1*c + q0*sn;
  float kr = k0*c - k1*sn, ki = k1*c + k0*sn;
  q[2*t] = qr; q[2*t+1] = qi;
  k[2*t] = kr; k[2*t+1] = ki;
  qs[2*t] = qr; qs[2*t+1] = qi;
  ks[2*t] = kr; ks[2*t+1] = ki;
  __syncthreads();
  if (t < HC) {
    int ch = sorted_channel[h*HC + t];
    qlab[(size_t)(b*NH + h)*HC + t] = qs[ch];
    klab[(size_t)(b*NH + h)*HC + t] = ks[ch];
  }
}

// ---------------- label scores (full GPU): 4 s-chunks per (b,h) ----------------
__global__ __launch_bounds__(256) void scores_k(const float* __restrict__ klab_cache,
                                                const float* __restrict__ qlab,
                                                const float* __restrict__ klab,
                                                const int* __restrict__ pos_p,
                                                uint32_t* __restrict__ su) {
  int bc = blockIdx.x; int c = bc & 3; int bh = bc >> 2;
  int b = bh >> 5; int h = bh & 31;
  int pos = *pos_p;
  int n = pos + 1;
  __shared__ float qv[HC];
  int t = threadIdx.x;
  if (t < HC) qv[t] = qlab[(size_t)bh*HC + t];
  __syncthreads();
  int chunk = (n + 3) >> 2;
  int s0 = c * chunk, s1 = min(n, s0 + chunk);
  for (int s = s0 + t; s < s1; s += 256) {
    const float* kl = (s == pos) ? (klab + (size_t)bh*HC)
                                 : (klab_cache + (((size_t)b*SEQ + s)*NH + h)*HC);
    const float4* kl4 = (const float4*)kl;
    float acc = 0.f;
    #pragma unroll
    for (int c4 = 0; c4 < HC/4; c4++) {
      float4 kvv = kl4[c4];
      acc += qv[c4*4+0]*kvv.x + qv[c4*4+1]*kvv.y + qv[c4*4+2]*kvv.z + qv[c4*4+3]*kvv.w;
    }
    uint32_t u = __float_as_uint(acc);
    u = (u & 0x80000000u) ? ~u : (u | 0x80000000u);   // monotone map, desc order
    su[(size_t)bh*SEQ + s] = u;
  }
}

// ---------------- radix-select top-256 from precomputed scores ----------------
__global__ __launch_bounds__(256) void select_k(const uint32_t* __restrict__ su_g,
                                                const int* __restrict__ pos_p,
                                                int* __restrict__ idx_out) {
  int bh = blockIdx.x;
  int pos = *pos_p;
  int n = pos + 1;
  __shared__ uint32_t su[SEQ];
  __shared__ uint32_t hist[256];
  __shared__ uint32_t sh_prefix, sh_kremain, sh_cnt;
  int tid = threadIdx.x;
  if (tid == 0) { sh_prefix = 0; sh_kremain = HEAVY; sh_cnt = 0; }
  for (int s = tid; s < n; s += 256) su[s] = su_g[(size_t)bh*SEQ + s];
  __syncthreads();
  uint32_t prefix = 0;
  #pragma unroll
  for (int pass = 0; pass < 4; pass++) {
    int shift = 24 - 8*pass;
    for (int i = tid; i < 256; i += 256) hist[i] = 0;
    __syncthreads();
    for (int s = tid; s < n; s += 256) {
      uint32_t u = su[s];
      bool match = (pass == 0) || ((u >> (shift + 8)) == prefix);
      if (match) atomicAdd(&hist[(u >> shift) & 255u], 1u);
    }
    __syncthreads();
    if (tid == 0) {
      uint32_t need = sh_kremain, c = 0;
      int d = 255;
      for (; d >= 0; d--) {
        if (c + hist[d] >= need) break;
        c += hist[d];
      }
      if (d < 0) d = 0;                 // safety
      sh_kremain = need - c;
      sh_prefix = (sh_prefix << 8) | (uint32_t)d;
    }
    __syncthreads();
    prefix = sh_prefix;
  }
  uint32_t T = prefix;                   // exact value of the 256th-largest
  int* outp = idx_out + (size_t)bh*HEAVY;
  for (int s = tid; s < n; s += 256) {
    if (su[s] > T) { uint32_t p = atomicAdd(&sh_cnt, 1u); outp[p] = s; }
  }
  __syncthreads();
  for (int s = tid; s < n; s += 256) {
    if (su[s] == T) {
      uint32_t p = atomicAdd(&sh_cnt, 1u);
      if (p < HEAVY) outp[p] = s;
    }
  }
}

// ---------------- gather attention over 256 selected tokens ----------------
__global__ __launch_bounds__(256) void attn_k(const float* __restrict__ k_cache,
                                              const float* __restrict__ v_cache,
                                              const float* __restrict__ qkv,
                                              const int* __restrict__ idx,
                                              const int* __restrict__ pos_p,
                                              float* __restrict__ o) {
  int bh = blockIdx.x; int b = bh >> 5; int h = bh & 31;
  int pos = *pos_p;
  int tid = threadIdx.x;
  __shared__ int lidx[HEAVY];
  __shared__ float sc[HEAVY];
  __shared__ float ov[256];
  __shared__ float red[8];
  __shared__ float s_m, s_sum;
  lidx[tid] = idx[(size_t)(b*NH + h)*HEAVY + tid];
  __syncthreads();
  const float* qp   = qkv + (size_t)b*3*DIM + h*HD;
  const float* knew = qp + DIM;
  const float* vnew = qp + 2*DIM;
  int g = tid >> 5, l = tid & 31;        // 8 groups of 32 lanes
  float4 q4 = ((const float4*)qp)[l];
  for (int j = g; j < HEAVY; j += 8) {
    int s = lidx[j];
    const float* kp = (s == pos) ? knew
                                 : (k_cache + (((size_t)b*SEQ + s)*NH + h)*HD);
    float4 k4 = ((const float4*)kp)[l];
    float p = dot4(q4, k4);
    #pragma unroll
    for (int off = 16; off; off >>= 1) p += __shfl_xor(p, off, 64);
    if (l == 0) sc[j] = p * 0.088388347648318447f;   // 1/sqrt(128)
  }
  __syncthreads();
  // softmax over the 256 scores; each thread owns sc[tid]
  float v = sc[tid];
  float m = v;
  #pragma unroll
  for (int off = 32; off; off >>= 1) m = fmaxf(m, __shfl_xor(m, off, 64));
  if ((tid & 63) == 0) red[tid >> 6] = m;
  __syncthreads();
  if (tid == 0) {
    float mm = red[0];
    for (int i = 1; i < 4; i++) mm = fmaxf(mm, red[i]);
    s_m = mm;
  }
  __syncthreads();
  float p = expf(v - s_m);
  float sum = p;
  #pragma unroll
  for (int off = 32; off; off >>= 1) sum += __shfl_xor(sum, off, 64);
  if ((tid & 63) == 0) red[4 + (tid >> 6)] = sum;
  __syncthreads();
  if (tid == 0) {
    float ss = 0;
    for (int i = 0; i < 4; i++) ss += red[4 + i];
    s_sum = ss;
  }
  __syncthreads();
  sc[tid] = p / s_sum;
  __syncthreads();
  // PV: threads 0..127 handle even j, 128..255 odd j; d = tid & 127
  int d = tid & 127, half = tid >> 7;
  float acc = 0.f;
  for (int j = half; j < HEAVY; j += 2) {
    int s = lidx[j];
    const float* vp = (s == pos) ? vnew
                                 : (v_cache + (((size_t)b*SEQ + s)*NH + h)*HD);
    acc += sc[j] * vp[d];
  }
  ov[tid] = acc;
  __syncthreads();
  if (tid < 128) o[(size_t)(b*NH + h)*HD + tid] = ov[tid] + ov[tid + 128];
}

extern "C" void kernel_launch(void* const* d_in, const int* in_sizes, int n_in,
                              void* d_out, int out_size, void* d_ws, size_t ws_size,
                              hipStream_t stream) {
  const float* x              = (const float*)d_in[0];
  const float* wqkv           = (const float*)d_in[1];
  const float* wo             = (const float*)d_in[2];
  const float* w1             = (const float*)d_in[3];
  const float* w2             = (const float*)d_in[4];
  const float* w3             = (const float*)d_in[5];
  const float* attn_norm_w    = (const float*)d_in[6];
  const float* ffn_norm_w     = (const float*)d_in[7];
  const float* k_cache        = (const float*)d_in[8];
  const float* v_cache        = (const float*)d_in[9];
  const float* k_label_cache  = (const float*)d_in[10];
  const float* freqs          = (const float*)d_in[11];
  // d_in[12] = mask1 (semantics: 0 for s<=pos, -1e9 else) — implemented via s range
  const int*   sorted_channel = (const int*)d_in[13];
  const int*   pos_p          = (const int*)d_in[14];
  // d_in[15] = heavy_const (fixed 256, hardcoded as HEAVY)

  float* ws  = (float*)d_ws;
  float* xn   = ws;                          // 4*4096
  float* qkv  = xn  + NB*DIM;                // 4*12288 (q,k roped in place)
  float* qlab = qkv + NB*3*DIM;              // 4*32*32
  float* klab = qlab + NB*NH*HC;             // 4*32*32
  int*   idx  = (int*)(klab + NB*NH*HC);     // 4*32*256
  float* o    = (float*)(idx + NB*NH*HEAVY); // 4*4096
  float* h    = o  + NB*DIM;                 // 4*4096
  float* hn   = h  + NB*DIM;                 // 4*4096
  float* g    = hn + NB*DIM;                 // 4*11008
  uint32_t* su = (uint32_t*)(g + NB*INTER);  // 4*32*4096

  rmsnorm_k            <<<NB,         256, 0, stream>>>(x, attn_norm_w, xn);
  gemv_reg_k<DIM, 8, false><<<3*DIM/8, 256, 0, stream>>>(wqkv, xn, nullptr, qkv, 3*DIM);
  rope_lab_k           <<<NB*NH,       64, 0, stream>>>(qkv, freqs, sorted_channel, qlab, klab);
  scores_k             <<<NB*NH*4,    256, 0, stream>>>(k_label_cache, qlab, klab, pos_p, su);
  select_k             <<<NB*NH,      256, 0, stream>>>(su, pos_p, idx);
  attn_k               <<<NB*NH,      256, 0, stream>>>(k_cache, v_cache, qkv, idx, pos_p, o);
  gemv_reg_k<DIM, 8, true><<<DIM/8,   256, 0, stream>>>(wo, o, x, h, DIM);
  rmsnorm_k            <<<NB,         256, 0, stream>>>(h, ffn_norm_w, hn);
  gemv_ffn13_k<4>      <<<INTER/4,    256, 0, stream>>>(w1, w3, hn, g);
  gemv_w2_k<8>         <<<DIM/8,      256, 0, stream>>>(w2, g, h, (float*)d_out);
}

// Round 3
// 303.531 us; speedup vs baseline: 1.2544x; 1.1699x over previous
//
#include <hip/hip_runtime.h>
#include <math.h>

#define NB 4
#define SEQ 4096
#define NH 32
#define HD 128
#define DIM 4096
#define INTER 11008
#define HC 32
#define HEAVY 256
#define EPS 1e-5f

typedef float f4 __attribute__((ext_vector_type(4)));

__device__ __forceinline__ float dotv(f4 a, f4 b) {
  f4 p = a * b;
  return p.x + p.y + p.z + p.w;
}
__device__ __forceinline__ f4 ldnt(const float* p) {
  return __builtin_nontemporal_load((const f4*)p);
}
__device__ __forceinline__ f4 ld4(const float* p) { return *(const f4*)p; }

__device__ __forceinline__ float wave_sum(float v) {
  #pragma unroll
  for (int off = 32; off; off >>= 1) v += __shfl_down(v, off, 64);
  return v;
}

// ---------- QKV GEMV with fused input RMSNorm. R rows/block, x in regs ----------
template<int R>
__global__ __launch_bounds__(256) void qkv_norm_k(const float* __restrict__ w,
                                                  const float* __restrict__ x,
                                                  const float* __restrict__ nw,
                                                  float* __restrict__ out) {
  const int t = threadIdx.x;
  const int r0 = blockIdx.x * R;
  f4 xr[NB][4];
  #pragma unroll
  for (int b = 0; b < NB; ++b)
    #pragma unroll
    for (int j = 0; j < 4; ++j)
      xr[b][j] = ld4(x + b*DIM + (j*256 + t)*4);
  // fused rmsnorm (computed redundantly per block; inputs are L2-hot)
  __shared__ float redn[4][NB];
  const int lane = t & 63, wi = t >> 6;
  #pragma unroll
  for (int b = 0; b < NB; ++b) {
    float ss = 0.f;
    #pragma unroll
    for (int j = 0; j < 4; ++j) ss += dotv(xr[b][j], xr[b][j]);
    ss = wave_sum(ss);
    if (lane == 0) redn[wi][b] = ss;
  }
  __syncthreads();
  float rs[NB];
  #pragma unroll
  for (int b = 0; b < NB; ++b)
    rs[b] = rsqrtf((redn[0][b]+redn[1][b]+redn[2][b]+redn[3][b]) * (1.f/DIM) + EPS);
  #pragma unroll
  for (int j = 0; j < 4; ++j) {
    f4 aw = ld4(nw + (j*256 + t)*4);
    #pragma unroll
    for (int b = 0; b < NB; ++b) xr[b][j] = xr[b][j] * rs[b] * aw;
  }
  float acc[R][NB];
  #pragma unroll
  for (int r = 0; r < R; ++r)
    #pragma unroll
    for (int b = 0; b < NB; ++b) acc[r][b] = 0.f;
  #pragma unroll
  for (int r = 0; r < R; ++r) {
    const float* wr = w + (size_t)(r0 + r) * DIM;
    #pragma unroll
    for (int j = 0; j < 4; ++j) {
      f4 wv = ldnt(wr + (j*256 + t)*4);
      #pragma unroll
      for (int b = 0; b < NB; ++b) acc[r][b] += dotv(wv, xr[b][j]);
    }
  }
  __shared__ float red[4][R*NB];
  #pragma unroll
  for (int r = 0; r < R; ++r)
    #pragma unroll
    for (int b = 0; b < NB; ++b) {
      float v = wave_sum(acc[r][b]);
      if (lane == 0) red[wi][r*NB + b] = v;
    }
  __syncthreads();
  if (t < R*NB) {
    int r = t >> 2, b = t & 3;
    float s = red[0][t] + red[1][t] + red[2][t] + red[3][t];
    out[(size_t)b*(3*DIM) + r0 + r] = s;
  }
}

// ---------- Wo GEMV + residual, R rows/block ----------
template<int R>
__global__ __launch_bounds__(256) void wo_k(const float* __restrict__ w,
                                            const float* __restrict__ x,
                                            const float* __restrict__ resid,
                                            float* __restrict__ out) {
  const int t = threadIdx.x;
  const int r0 = blockIdx.x * R;
  f4 xr[NB][4];
  #pragma unroll
  for (int b = 0; b < NB; ++b)
    #pragma unroll
    for (int j = 0; j < 4; ++j)
      xr[b][j] = ld4(x + b*DIM + (j*256 + t)*4);
  float acc[R][NB];
  #pragma unroll
  for (int r = 0; r < R; ++r)
    #pragma unroll
    for (int b = 0; b < NB; ++b) acc[r][b] = 0.f;
  #pragma unroll
  for (int r = 0; r < R; ++r) {
    const float* wr = w + (size_t)(r0 + r) * DIM;
    #pragma unroll
    for (int j = 0; j < 4; ++j) {
      f4 wv = ldnt(wr + (j*256 + t)*4);
      #pragma unroll
      for (int b = 0; b < NB; ++b) acc[r][b] += dotv(wv, xr[b][j]);
    }
  }
  __shared__ float red[4][R*NB];
  const int lane = t & 63, wi = t >> 6;
  #pragma unroll
  for (int r = 0; r < R; ++r)
    #pragma unroll
    for (int b = 0; b < NB; ++b) {
      float v = wave_sum(acc[r][b]);
      if (lane == 0) red[wi][r*NB + b] = v;
    }
  __syncthreads();
  if (t < R*NB) {
    int r = t >> 2, b = t & 3;
    float s = red[0][t] + red[1][t] + red[2][t] + red[3][t];
    out[(size_t)b*DIM + r0 + r] = resid[(size_t)b*DIM + r0 + r] + s;
  }
}

// ---------- W1/W3 GEMV + SwiGLU with fused input RMSNorm ----------
template<int R>
__global__ __launch_bounds__(256) void ffn13_norm_k(const float* __restrict__ w1,
                                                    const float* __restrict__ w3,
                                                    const float* __restrict__ h,
                                                    const float* __restrict__ nw,
                                                    float* __restrict__ g) {
  const int t = threadIdx.x;
  const int r0 = blockIdx.x * R;
  f4 xr[NB][4];
  #pragma unroll
  for (int b = 0; b < NB; ++b)
    #pragma unroll
    for (int j = 0; j < 4; ++j)
      xr[b][j] = ld4(h + b*DIM + (j*256 + t)*4);
  __shared__ float redn[4][NB];
  const int lane = t & 63, wi = t >> 6;
  #pragma unroll
  for (int b = 0; b < NB; ++b) {
    float ss = 0.f;
    #pragma unroll
    for (int j = 0; j < 4; ++j) ss += dotv(xr[b][j], xr[b][j]);
    ss = wave_sum(ss);
    if (lane == 0) redn[wi][b] = ss;
  }
  __syncthreads();
  float rs[NB];
  #pragma unroll
  for (int b = 0; b < NB; ++b)
    rs[b] = rsqrtf((redn[0][b]+redn[1][b]+redn[2][b]+redn[3][b]) * (1.f/DIM) + EPS);
  #pragma unroll
  for (int j = 0; j < 4; ++j) {
    f4 aw = ld4(nw + (j*256 + t)*4);
    #pragma unroll
    for (int b = 0; b < NB; ++b) xr[b][j] = xr[b][j] * rs[b] * aw;
  }
  float a1[R][NB], a3[R][NB];
  #pragma unroll
  for (int r = 0; r < R; ++r)
    #pragma unroll
    for (int b = 0; b < NB; ++b) { a1[r][b] = 0.f; a3[r][b] = 0.f; }
  #pragma unroll
  for (int r = 0; r < R; ++r) {
    const float* wr1 = w1 + (size_t)(r0 + r) * DIM;
    const float* wr3 = w3 + (size_t)(r0 + r) * DIM;
    #pragma unroll
    for (int j = 0; j < 4; ++j) {
      f4 v1 = ldnt(wr1 + (j*256 + t)*4);
      f4 v3 = ldnt(wr3 + (j*256 + t)*4);
      #pragma unroll
      for (int b = 0; b < NB; ++b) {
        a1[r][b] += dotv(v1, xr[b][j]);
        a3[r][b] += dotv(v3, xr[b][j]);
      }
    }
  }
  __shared__ float red[4][2*R*NB];
  #pragma unroll
  for (int r = 0; r < R; ++r)
    #pragma unroll
    for (int b = 0; b < NB; ++b) {
      float v = wave_sum(a1[r][b]);
      if (lane == 0) red[wi][r*NB + b] = v;
      v = wave_sum(a3[r][b]);
      if (lane == 0) red[wi][R*NB + r*NB + b] = v;
    }
  __syncthreads();
  if (t < R*NB) {
    int r = t >> 2, b = t & 3;
    float d1 = red[0][t] + red[1][t] + red[2][t] + red[3][t];
    int t3 = R*NB + t;
    float d3 = red[0][t3] + red[1][t3] + red[2][t3] + red[3][t3];
    float s = d1 / (1.f + expf(-d1));
    g[(size_t)b*INTER + r0 + r] = s * d3;
  }
}

// ---------- W2 GEMV (K=11008): LDS-tiled x, + residual -> final out ----------
template<int R>
__global__ __launch_bounds__(256) void w2_k(const float* __restrict__ w2,
                                            const float* __restrict__ g,
                                            const float* __restrict__ h,
                                            float* __restrict__ out) {
  const int t = threadIdx.x;
  const int r0 = blockIdx.x * R;
  __shared__ f4 xs[NB][256];
  float acc[R][NB];
  #pragma unroll
  for (int r = 0; r < R; ++r)
    #pragma unroll
    for (int b = 0; b < NB; ++b) acc[r][b] = 0.f;
  for (int k0 = 0; k0 < INTER; k0 += 1024) {
    const int kn4 = min(256, (INTER - k0) >> 2);
    __syncthreads();
    if (t < kn4) {
      #pragma unroll
      for (int b = 0; b < NB; ++b)
        xs[b][t] = ld4(g + (size_t)b*INTER + k0 + t*4);
    }
    __syncthreads();
    if (t < kn4) {
      #pragma unroll
      for (int r = 0; r < R; ++r) {
        f4 wv = ldnt(w2 + (size_t)(r0 + r)*INTER + k0 + t*4);
        #pragma unroll
        for (int b = 0; b < NB; ++b) acc[r][b] += dotv(wv, xs[b][t]);
      }
    }
  }
  __shared__ float red[4][R*NB];
  const int lane = t & 63, wi = t >> 6;
  #pragma unroll
  for (int r = 0; r < R; ++r)
    #pragma unroll
    for (int b = 0; b < NB; ++b) {
      float v = wave_sum(acc[r][b]);
      if (lane == 0) red[wi][r*NB + b] = v;
    }
  __syncthreads();
  if (t < R*NB) {
    int r = t >> 2, b = t & 3;
    float s = red[0][t] + red[1][t] + red[2][t] + red[3][t];
    out[(size_t)b*DIM + r0 + r] = h[(size_t)b*DIM + r0 + r] + s;
  }
}

// ---------- fused RoPE + label scores: 4 s-chunks per (b,h) ----------
__global__ __launch_bounds__(256) void scores_rope_k(const float* __restrict__ qkv,
                                                     const float* __restrict__ freqs,
                                                     const int* __restrict__ chan,
                                                     const float* __restrict__ klab_cache,
                                                     const int* __restrict__ pos_p,
                                                     uint32_t* __restrict__ su,
                                                     float* __restrict__ q_rot,
                                                     float* __restrict__ k_rot) {
  int bc = blockIdx.x; int c = bc & 3; int bh = bc >> 2;
  int b = bh >> 5, h = bh & 31;
  int pos = *pos_p; int n = pos + 1;
  int t = threadIdx.x;
  __shared__ float qs[HD], ks[HD], qv[HC], kls[HC];
  const float* qp = qkv + (size_t)b*3*DIM + h*HD;
  const float* kp = qp + DIM;
  if (t < 64) {
    float cc = freqs[2*t], sn = freqs[2*t+1];
    float q0 = qp[2*t], q1 = qp[2*t+1];
    float k0 = kp[2*t], k1 = kp[2*t+1];
    qs[2*t] = q0*cc - q1*sn; qs[2*t+1] = q1*cc + q0*sn;
    ks[2*t] = k0*cc - k1*sn; ks[2*t+1] = k1*cc + k0*sn;
  }
  __syncthreads();
  if (t < HC) { int ch = chan[h*HC + t]; qv[t] = qs[ch]; kls[t] = ks[ch]; }
  if (c == 0 && t < HD) {
    q_rot[(size_t)bh*HD + t] = qs[t];
    k_rot[(size_t)bh*HD + t] = ks[t];
  }
  __syncthreads();
  int chunk = (n + 3) >> 2;
  int s0 = c * chunk, s1 = min(n, s0 + chunk);
  for (int s = s0 + t; s < s1; s += 256) {
    float acc = 0.f;
    if (s == pos) {
      #pragma unroll
      for (int j = 0; j < HC; ++j) acc += qv[j] * kls[j];
    } else {
      const float* kl = klab_cache + (((size_t)b*SEQ + s)*NH + h)*HC;
      #pragma unroll
      for (int c4 = 0; c4 < HC/4; ++c4) {
        f4 kv = ldnt(kl + c4*4);
        acc += qv[c4*4+0]*kv.x + qv[c4*4+1]*kv.y + qv[c4*4+2]*kv.z + qv[c4*4+3]*kv.w;
      }
    }
    uint32_t u = __float_as_uint(acc);
    u = (u & 0x80000000u) ? ~u : (u | 0x80000000u);   // monotone map, desc order
    su[(size_t)bh*SEQ + s] = u;
  }
}

// ---------- fused radix-select top-256 (parallel scan) + gather attention ----------
__global__ __launch_bounds__(256) void selattn_k(const uint32_t* __restrict__ su_g,
                                                 const float* __restrict__ q_rot,
                                                 const float* __restrict__ k_rot,
                                                 const float* __restrict__ qkv,
                                                 const float* __restrict__ k_cache,
                                                 const float* __restrict__ v_cache,
                                                 const int* __restrict__ pos_p,
                                                 float* __restrict__ o) {
  int bh = blockIdx.x; int b = bh >> 5, h = bh & 31;
  int pos = *pos_p; int n = pos + 1;
  int t = threadIdx.x;
  __shared__ uint32_t su[SEQ];
  __shared__ uint32_t hist[256], sfx[256];
  __shared__ uint32_t sh_prefix, sh_kremain, sh_cnt;
  __shared__ int lidx[HEAVY];
  __shared__ float sc[HEAVY], ov[256], red[8];
  __shared__ float s_m, s_sum;
  if (t == 0) { sh_prefix = 0; sh_kremain = HEAVY; sh_cnt = 0; }
  for (int s = t; s < n; s += 256) su[s] = su_g[(size_t)bh*SEQ + s];
  __syncthreads();
  uint32_t prefix = 0;
  for (int pass = 0; pass < 4; ++pass) {
    int shift = 24 - 8*pass;
    hist[t] = 0;
    __syncthreads();
    for (int s = t; s < n; s += 256) {
      uint32_t u = su[s];
      bool m = (pass == 0) || ((u >> (shift + 8)) == prefix);
      if (m) atomicAdd(&hist[(u >> shift) & 255u], 1u);
    }
    __syncthreads();
    uint32_t need = sh_kremain;
    sfx[t] = hist[t];
    __syncthreads();
    #pragma unroll
    for (int off = 1; off < 256; off <<= 1) {
      uint32_t v = sfx[t];
      uint32_t a = (t + off < 256) ? sfx[t + off] : 0u;
      __syncthreads();
      sfx[t] = v + a;
      __syncthreads();
    }
    // sfx[t] = count of elements with digit >= t; find largest t with sfx[t] >= need
    if (sfx[t] >= need && (t == 255 || sfx[t+1] < need)) {
      sh_prefix = (prefix << 8) | (uint32_t)t;
      sh_kremain = need - ((t == 255) ? 0u : sfx[t+1]);
    }
    __syncthreads();
    prefix = sh_prefix;
  }
  uint32_t T = prefix;   // exact bit pattern of the 256th-largest score
  for (int s = t; s < n; s += 256)
    if (su[s] > T) { uint32_t p = atomicAdd(&sh_cnt, 1u); lidx[p] = s; }
  __syncthreads();
  for (int s = t; s < n; s += 256)
    if (su[s] == T) {
      uint32_t p = atomicAdd(&sh_cnt, 1u);
      if (p < HEAVY) lidx[p] = s;
    }
  __syncthreads();
  // ---- attention over the 256 selected tokens ----
  const float* qp   = q_rot + (size_t)bh*HD;
  const float* knew = k_rot + (size_t)bh*HD;
  const float* vnew = qkv + (size_t)b*3*DIM + 2*DIM + h*HD;
  int gg = t >> 5, l = t & 31;
  f4 q4 = ((const f4*)qp)[l];
  for (int j = gg; j < HEAVY; j += 8) {
    int s = lidx[j];
    const float* kp = (s == pos) ? knew
                                 : (k_cache + (((size_t)b*SEQ + s)*NH + h)*HD);
    f4 k4 = ((const f4*)kp)[l];
    float p = dotv(q4, k4);
    #pragma unroll
    for (int off = 16; off; off >>= 1) p += __shfl_xor(p, off, 64);
    if (l == 0) sc[j] = p * 0.088388347648318447f;   // 1/sqrt(128)
  }
  __syncthreads();
  float v = sc[t];
  float m = v;
  #pragma unroll
  for (int off = 32; off; off >>= 1) m = fmaxf(m, __shfl_xor(m, off, 64));
  if ((t & 63) == 0) red[t >> 6] = m;
  __syncthreads();
  if (t == 0) {
    float mm = red[0];
    for (int i = 1; i < 4; i++) mm = fmaxf(mm, red[i]);
    s_m = mm;
  }
  __syncthreads();
  float p = expf(v - s_m);
  float sum = p;
  #pragma unroll
  for (int off = 32; off; off >>= 1) sum += __shfl_xor(sum, off, 64);
  if ((t & 63) == 0) red[4 + (t >> 6)] = sum;
  __syncthreads();
  if (t == 0) {
    float ss = 0;
    for (int i = 0; i < 4; i++) ss += red[4 + i];
    s_sum = ss;
  }
  __syncthreads();
  sc[t] = p / s_sum;
  __syncthreads();
  int d = t & 127, half = t >> 7;
  float acc = 0.f;
  for (int j = half; j < HEAVY; j += 2) {
    int s = lidx[j];
    const float* vp = (s == pos) ? vnew
                                 : (v_cache + (((size_t)b*SEQ + s)*NH + h)*HD);
    acc += sc[j] * vp[d];
  }
  ov[t] = acc;
  __syncthreads();
  if (t < 128) o[(size_t)bh*HD + t] = ov[t] + ov[t + 128];
}

extern "C" void kernel_launch(void* const* d_in, const int* in_sizes, int n_in,
                              void* d_out, int out_size, void* d_ws, size_t ws_size,
                              hipStream_t stream) {
  const float* x              = (const float*)d_in[0];
  const float* wqkv           = (const float*)d_in[1];
  const float* wo             = (const float*)d_in[2];
  const float* w1             = (const float*)d_in[3];
  const float* w2             = (const float*)d_in[4];
  const float* w3             = (const float*)d_in[5];
  const float* attn_norm_w    = (const float*)d_in[6];
  const float* ffn_norm_w     = (const float*)d_in[7];
  const float* k_cache        = (const float*)d_in[8];
  const float* v_cache        = (const float*)d_in[9];
  const float* k_label_cache  = (const float*)d_in[10];
  const float* freqs          = (const float*)d_in[11];
  // d_in[12] = mask1 (0 for s<=pos, -1e9 else) — realized via the s<n range
  const int*   sorted_channel = (const int*)d_in[13];
  const int*   pos_p          = (const int*)d_in[14];
  // d_in[15] = heavy_const (256, hardcoded)

  float* ws   = (float*)d_ws;
  float* qkv  = ws;                           // 4*12288
  float* q_rot = qkv + NB*3*DIM;              // 4*32*128
  float* k_rot = q_rot + NB*NH*HD;            // 4*32*128
  float* o    = k_rot + NB*NH*HD;             // 4*4096
  float* h    = o + NB*DIM;                   // 4*4096
  float* g    = h + NB*DIM;                   // 4*11008
  uint32_t* su = (uint32_t*)(g + NB*INTER);   // 4*32*4096

  qkv_norm_k<8> <<<3*DIM/8, 256, 0, stream>>>(wqkv, x, attn_norm_w, qkv);
  scores_rope_k <<<NB*NH*4, 256, 0, stream>>>(qkv, freqs, sorted_channel,
                                              k_label_cache, pos_p, su, q_rot, k_rot);
  selattn_k     <<<NB*NH,   256, 0, stream>>>(su, q_rot, k_rot, qkv,
                                              k_cache, v_cache, pos_p, o);
  wo_k<4>       <<<DIM/4,   256, 0, stream>>>(wo, o, x, h);
  ffn13_norm_k<4><<<INTER/4,256, 0, stream>>>(w1, w3, h, ffn_norm_w, g);
  w2_k<4>       <<<DIM/4,   256, 0, stream>>>(w2, g, h, (float*)d_out);
}